// Round 4
// baseline (383.830 us; speedup 1.0000x reference)
//
#include <hip/hip_runtime.h>

#define N_NODES 50000
#define N_EDGES 1600000
#define N_HEAD 4
#define F_OUT 128
#define CAP 96        // Poisson(32) out-degree; P(any node > 96) ~ 5e-14
#define CSTRIDE 16    // one counter per 64B cache line

// ---------------- K1: per-node scores, packed float4 (h0..h3) per node ----------
__global__ void __launch_bounds__(256) score_kernel(
    const float* __restrict__ x, const float* __restrict__ w,
    const float* __restrict__ a, float4* __restrict__ s_src4,
    float4* __restrict__ s_dst4) {
  int wv = (blockIdx.x * blockDim.x + threadIdx.x) >> 6;
  int lane = threadIdx.x & 63;
  if (wv >= N_NODES) return;
  float xv0 = x[wv * F_OUT + lane];
  float xv1 = x[wv * F_OUT + 64 + lane];
  float ps[N_HEAD], pd[N_HEAD];
#pragma unroll
  for (int h = 0; h < N_HEAD; ++h) {
    float w0 = w[h * F_OUT + lane];
    float w1 = w[h * F_OUT + 64 + lane];
    float as0 = a[h * 2 * F_OUT + lane];
    float as1 = a[h * 2 * F_OUT + 64 + lane];
    float ad0 = a[h * 2 * F_OUT + F_OUT + lane];
    float ad1 = a[h * 2 * F_OUT + F_OUT + 64 + lane];
    ps[h] = xv0 * w0 * as0 + xv1 * w1 * as1;
    pd[h] = xv0 * w0 * ad0 + xv1 * w1 * ad1;
  }
#pragma unroll
  for (int off = 32; off > 0; off >>= 1) {
#pragma unroll
    for (int h = 0; h < N_HEAD; ++h) {
      ps[h] += __shfl_xor(ps[h], off, 64);
      pd[h] += __shfl_xor(pd[h], off, 64);
    }
  }
  if (lane == 0) {
    s_src4[wv] = make_float4(ps[0], ps[1], ps[2], ps[3]);
    s_dst4[wv] = make_float4(pd[0], pd[1], pd[2], pd[3]);
  }
}

// ---------------- K2: bucket scatter, 4 independent edges per thread ------------
__global__ void __launch_bounds__(256) scatter_kernel(
    const int4* __restrict__ src4, const int4* __restrict__ dst4,
    int* __restrict__ cnt, int* __restrict__ bucket) {
  int t = blockIdx.x * blockDim.x + threadIdx.x;
  if (t >= N_EDGES / 4) return;
  int4 s = src4[t];
  int4 d = dst4[t];
  // 4 independent atomic chains -> 4x memory-level parallelism per lane
  int p0 = atomicAdd(&cnt[s.x * CSTRIDE], 1);
  int p1 = atomicAdd(&cnt[s.y * CSTRIDE], 1);
  int p2 = atomicAdd(&cnt[s.z * CSTRIDE], 1);
  int p3 = atomicAdd(&cnt[s.w * CSTRIDE], 1);
  if (p0 < CAP) bucket[s.x * CAP + p0] = d.x;
  if (p1 < CAP) bucket[s.y * CAP + p1] = d.y;
  if (p2 < CAP) bucket[s.z * CAP + p2] = d.z;
  if (p3 < CAP) bucket[s.w * CAP + p3] = d.w;
}

// ---------------- K3: gather/accumulate, one wave per node ----------------------
__global__ void __launch_bounds__(256) agg_kernel(
    const float* __restrict__ x, const float* __restrict__ w,
    const float4* __restrict__ s_src4, const float4* __restrict__ s_dst4,
    const int* __restrict__ cnt, const int* __restrict__ bucket,
    float* __restrict__ out) {
  __shared__ int lds_d[4][CAP];
  __shared__ float4 lds_w[4][CAP];
  int wv = (blockIdx.x * blockDim.x + threadIdx.x) >> 6;
  int lane = threadIdx.x & 63;
  int ws = threadIdx.x >> 6;
  if (wv >= N_NODES) return;
  const int n = wv;
  int m = cnt[n * CSTRIDE];
  m = (m < CAP) ? m : CAP;
  float4 ss = s_src4[n];

  // ---- Phase A: 1 lane per edge computes weights, stash in wave-private LDS ----
  float p0 = 0.f, p1 = 0.f, p2 = 0.f, p3 = 0.f;
  for (int j = lane; j < m; j += 64) {
    int d = bucket[n * CAP + j];
    float4 sd = s_dst4[d];
    float sc0 = ss.x + sd.x, sc1 = ss.y + sd.y, sc2 = ss.z + sd.z, sc3 = ss.w + sd.w;
    float e0 = __expf(-fmaxf(sc0, 0.2f * sc0));
    float e1 = __expf(-fmaxf(sc1, 0.2f * sc1));
    float e2 = __expf(-fmaxf(sc2, 0.2f * sc2));
    float e3 = __expf(-fmaxf(sc3, 0.2f * sc3));
    lds_d[ws][j] = d;
    lds_w[ws][j] = make_float4(e0, e1, e2, e3);
    p0 += e0; p1 += e1; p2 += e2; p3 += e3;
  }
#pragma unroll
  for (int off = 32; off > 0; off >>= 1) {
    p0 += __shfl_xor(p0, off, 64);
    p1 += __shfl_xor(p1, off, 64);
    p2 += __shfl_xor(p2, off, 64);
    p3 += __shfl_xor(p3, off, 64);
  }

  // ---- Phase B: unroll x4 -> 4 outstanding x-row gathers per lane ----
  float2 a0 = {0.f, 0.f}, a1 = {0.f, 0.f}, a2 = {0.f, 0.f}, a3 = {0.f, 0.f};
  const float* xp = x + 2 * lane;
  int j = 0;
  for (; j + 3 < m; j += 4) {
    int d0 = lds_d[ws][j];
    int d1 = lds_d[ws][j + 1];
    int d2 = lds_d[ws][j + 2];
    int d3 = lds_d[ws][j + 3];
    float4 w0 = lds_w[ws][j];
    float4 w1 = lds_w[ws][j + 1];
    float4 w2 = lds_w[ws][j + 2];
    float4 w3 = lds_w[ws][j + 3];
    float2 x0 = *(const float2*)(xp + (size_t)d0 * F_OUT);
    float2 x1 = *(const float2*)(xp + (size_t)d1 * F_OUT);
    float2 x2 = *(const float2*)(xp + (size_t)d2 * F_OUT);
    float2 x3 = *(const float2*)(xp + (size_t)d3 * F_OUT);
    a0.x = fmaf(w0.x, x0.x, a0.x); a0.y = fmaf(w0.x, x0.y, a0.y);
    a1.x = fmaf(w0.y, x0.x, a1.x); a1.y = fmaf(w0.y, x0.y, a1.y);
    a2.x = fmaf(w0.z, x0.x, a2.x); a2.y = fmaf(w0.z, x0.y, a2.y);
    a3.x = fmaf(w0.w, x0.x, a3.x); a3.y = fmaf(w0.w, x0.y, a3.y);
    a0.x = fmaf(w1.x, x1.x, a0.x); a0.y = fmaf(w1.x, x1.y, a0.y);
    a1.x = fmaf(w1.y, x1.x, a1.x); a1.y = fmaf(w1.y, x1.y, a1.y);
    a2.x = fmaf(w1.z, x1.x, a2.x); a2.y = fmaf(w1.z, x1.y, a2.y);
    a3.x = fmaf(w1.w, x1.x, a3.x); a3.y = fmaf(w1.w, x1.y, a3.y);
    a0.x = fmaf(w2.x, x2.x, a0.x); a0.y = fmaf(w2.x, x2.y, a0.y);
    a1.x = fmaf(w2.y, x2.x, a1.x); a1.y = fmaf(w2.y, x2.y, a1.y);
    a2.x = fmaf(w2.z, x2.x, a2.x); a2.y = fmaf(w2.z, x2.y, a2.y);
    a3.x = fmaf(w2.w, x2.x, a3.x); a3.y = fmaf(w2.w, x2.y, a3.y);
    a0.x = fmaf(w3.x, x3.x, a0.x); a0.y = fmaf(w3.x, x3.y, a0.y);
    a1.x = fmaf(w3.y, x3.x, a1.x); a1.y = fmaf(w3.y, x3.y, a1.y);
    a2.x = fmaf(w3.z, x3.x, a2.x); a2.y = fmaf(w3.z, x3.y, a2.y);
    a3.x = fmaf(w3.w, x3.x, a3.x); a3.y = fmaf(w3.w, x3.y, a3.y);
  }
  for (; j < m; ++j) {
    int d0 = lds_d[ws][j];
    float4 w0 = lds_w[ws][j];
    float2 x0 = *(const float2*)(xp + (size_t)d0 * F_OUT);
    a0.x = fmaf(w0.x, x0.x, a0.x); a0.y = fmaf(w0.x, x0.y, a0.y);
    a1.x = fmaf(w0.y, x0.x, a1.x); a1.y = fmaf(w0.y, x0.y, a1.y);
    a2.x = fmaf(w0.z, x0.x, a2.x); a2.y = fmaf(w0.z, x0.y, a2.y);
    a3.x = fmaf(w0.w, x0.x, a3.x); a3.y = fmaf(w0.w, x0.y, a3.y);
  }

  // ---- epilogue ----
  const float2 wl0 = *(const float2*)(w + 0 * F_OUT + 2 * lane);
  const float2 wl1 = *(const float2*)(w + 1 * F_OUT + 2 * lane);
  const float2 wl2 = *(const float2*)(w + 2 * F_OUT + 2 * lane);
  const float2 wl3 = *(const float2*)(w + 3 * F_OUT + 2 * lane);
  float r0 = 1.f / p0, r1 = 1.f / p1, r2 = 1.f / p2, r3 = 1.f / p3;

  float2 o;
  o.x = wl0.x * a0.x * r0; o.y = wl0.y * a0.y * r0;
  *(float2*)(out + ((size_t)0 * N_NODES + n) * F_OUT + 2 * lane) = o;
  o.x = wl1.x * a1.x * r1; o.y = wl1.y * a1.y * r1;
  *(float2*)(out + ((size_t)1 * N_NODES + n) * F_OUT + 2 * lane) = o;
  o.x = wl2.x * a2.x * r2; o.y = wl2.y * a2.y * r2;
  *(float2*)(out + ((size_t)2 * N_NODES + n) * F_OUT + 2 * lane) = o;
  o.x = wl3.x * a3.x * r3; o.y = wl3.y * a3.y * r3;
  *(float2*)(out + ((size_t)3 * N_NODES + n) * F_OUT + 2 * lane) = o;
}

extern "C" void kernel_launch(void* const* d_in, const int* in_sizes, int n_in,
                              void* d_out, int out_size, void* d_ws, size_t ws_size,
                              hipStream_t stream) {
  const float* x = (const float*)d_in[0];
  const float* w = (const float*)d_in[1];
  const float* a = (const float*)d_in[2];
  const int* ei = (const int*)d_in[3];
  const int* src = ei;
  const int* dst = ei + N_EDGES;
  float* out = (float*)d_out;

  char* p = (char*)d_ws;
  float4* s_src4 = (float4*)p; p += (size_t)N_NODES * 16;
  float4* s_dst4 = (float4*)p; p += (size_t)N_NODES * 16;
  int* bucket   = (int*)p;    p += (size_t)N_NODES * CAP * 4;        // 19.2 MB
  int* cnt      = (int*)p;    p += (size_t)N_NODES * CSTRIDE * 4;    // 3.2 MB

  hipMemsetAsync(cnt, 0, (size_t)N_NODES * CSTRIDE * 4, stream);

  score_kernel<<<(N_NODES * 64 + 255) / 256, 256, 0, stream>>>(x, w, a, s_src4, s_dst4);
  scatter_kernel<<<(N_EDGES / 4 + 255) / 256, 256, 0, stream>>>(
      (const int4*)src, (const int4*)dst, cnt, bucket);
  agg_kernel<<<(N_NODES * 64 + 255) / 256, 256, 0, stream>>>(x, w, s_src4, s_dst4,
                                                             cnt, bucket, out);
}

// Round 5
// 308.934 us; speedup vs baseline: 1.2424x; 1.2424x over previous
//
#include <hip/hip_runtime.h>

#define N_NODES 50000
#define N_EDGES 1600000
#define N_HEAD 4
#define F_OUT 128
#define CAP 96        // per-node bucket capacity; Poisson(32), P(>96) ~ 5e-14
#define NPS 512       // nodes per super-bucket
#define K1 98         // ceil(50000/512)
#define SCAP 17408    // super capacity: mean 16384 + 8 sigma(128)
#define NPG 32        // nodes per agg block
#define GROUPS 1563   // ceil(50000/32)
#define EPB 4096      // edges per partition block
#define P1_BLOCKS ((N_EDGES + EPB - 1) / EPB)   // 391

// ---------------- K1: per-node scores, packed float4 (h0..h3) per node ----------
__global__ void __launch_bounds__(256) score_kernel(
    const float* __restrict__ x, const float* __restrict__ w,
    const float* __restrict__ a, float4* __restrict__ s_src4,
    float4* __restrict__ s_dst4) {
  int wv = (blockIdx.x * blockDim.x + threadIdx.x) >> 6;
  int lane = threadIdx.x & 63;
  if (wv >= N_NODES) return;
  float xv0 = x[wv * F_OUT + lane];
  float xv1 = x[wv * F_OUT + 64 + lane];
  float ps[N_HEAD], pd[N_HEAD];
#pragma unroll
  for (int h = 0; h < N_HEAD; ++h) {
    float w0 = w[h * F_OUT + lane];
    float w1 = w[h * F_OUT + 64 + lane];
    float as0 = a[h * 2 * F_OUT + lane];
    float as1 = a[h * 2 * F_OUT + 64 + lane];
    float ad0 = a[h * 2 * F_OUT + F_OUT + lane];
    float ad1 = a[h * 2 * F_OUT + F_OUT + 64 + lane];
    ps[h] = xv0 * w0 * as0 + xv1 * w1 * as1;
    pd[h] = xv0 * w0 * ad0 + xv1 * w1 * ad1;
  }
#pragma unroll
  for (int off = 32; off > 0; off >>= 1) {
#pragma unroll
    for (int h = 0; h < N_HEAD; ++h) {
      ps[h] += __shfl_xor(ps[h], off, 64);
      pd[h] += __shfl_xor(pd[h], off, 64);
    }
  }
  if (lane == 0) {
    s_src4[wv] = make_float4(ps[0], ps[1], ps[2], ps[3]);
    s_dst4[wv] = make_float4(pd[0], pd[1], pd[2], pd[3]);
  }
}

// ---------------- K2: block-local counting sort -> coalesced run writes ---------
// Packs (src<<16)|dst (both < 65536). Coarse bucket = src>>9 (=packed>>25).
__global__ void __launch_bounds__(256) partition_kernel(
    const int* __restrict__ src, const int* __restrict__ dst,
    int* __restrict__ gc, unsigned int* __restrict__ region) {
  __shared__ int hist[K1], cur[K1], lstart[K1], gpos[K1];
  __shared__ unsigned int staging[EPB];
  const int tid = threadIdx.x;
  const int base = blockIdx.x * EPB;
  int vc = N_EDGES - base;
  if (vc > EPB) vc = EPB;

  unsigned int pk[EPB / 256];
#pragma unroll
  for (int k = 0; k < EPB / 256; ++k) {
    int i = k * 256 + tid;
    if (i < vc) {
      unsigned int s = (unsigned int)src[base + i];
      unsigned int d = (unsigned int)dst[base + i];
      pk[k] = (s << 16) | d;           // valid packed can never be 0xffffffff
    } else {
      pk[k] = 0xffffffffu;
    }
  }
  if (tid < K1) { hist[tid] = 0; cur[tid] = 0; }
  __syncthreads();
#pragma unroll
  for (int k = 0; k < EPB / 256; ++k)
    if (pk[k] != 0xffffffffu) atomicAdd(&hist[pk[k] >> 25], 1);
  __syncthreads();
  // wave 0: exclusive scan of hist + global reservation
  if (tid < 64) {
    int carry = 0;
    for (int b0 = 0; b0 < K1; b0 += 64) {
      int idx = b0 + tid;
      int h = (idx < K1) ? hist[idx] : 0;
      int v = h;
#pragma unroll
      for (int off = 1; off < 64; off <<= 1) {
        int t = __shfl_up(v, off, 64);
        if (tid >= off) v += t;
      }
      if (idx < K1) {
        lstart[idx] = carry + v - h;
        gpos[idx] = atomicAdd(&gc[idx], h);
      }
      carry += __shfl(v, 63, 64);
    }
  }
  __syncthreads();
  // place into LDS staging, sorted by coarse bucket
#pragma unroll
  for (int k = 0; k < EPB / 256; ++k) {
    if (pk[k] != 0xffffffffu) {
      int b = pk[k] >> 25;
      int pos = lstart[b] + atomicAdd(&cur[b], 1);
      staging[pos] = pk[k];
    }
  }
  __syncthreads();
  // copy out: consecutive lanes -> consecutive global addresses within each run
  for (int i = tid; i < vc; i += 256) {
    unsigned int v = staging[i];
    int b = v >> 25;
    int off = gpos[b] + (i - lstart[b]);
    if (off < SCAP) region[(size_t)b * SCAP + off] = v;
  }
}

// ---------------- K3: fused LDS-bucket + gather/accumulate ----------------------
// One block per 32-node group; scans its super region, LDS-buckets its edges,
// then wave-per-node phase A (weights) / phase B (x-gather + FMA).
__global__ void __launch_bounds__(256) agg_kernel(
    const float* __restrict__ x, const float* __restrict__ w,
    const float4* __restrict__ s_src4, const float4* __restrict__ s_dst4,
    const int* __restrict__ gc, const unsigned int* __restrict__ region,
    float* __restrict__ out) {
  __shared__ int ncnt[NPG];
  __shared__ int nbkt[NPG][CAP];
  __shared__ float4 lds_w[4][CAP];
  const int tid = threadIdx.x;
  const int g = blockIdx.x;
  const int sb = g >> 4;                 // 16 groups per super (512/32)
  int c = gc[sb];
  if (c > SCAP) c = SCAP;
  if (tid < NPG) ncnt[tid] = 0;
  __syncthreads();

  const unsigned int* reg = region + (size_t)sb * SCAP;
  const unsigned int gtag = (unsigned int)g;
  for (int i = tid; i < c; i += 256) {
    unsigned int v = reg[i];
    unsigned int s = v >> 16;
    if ((s >> 5) == gtag) {
      int l = s & 31;
      int p = atomicAdd(&ncnt[l], 1);
      if (p < CAP) nbkt[l][p] = (int)(v & 0xffffu);
    }
  }
  __syncthreads();

  const int ws = tid >> 6, lane = tid & 63;
  const float* xp = x + 2 * lane;

  for (int l = ws; l < NPG; l += 4) {
    int n = g * NPG + l;
    if (n >= N_NODES) break;
    int m = ncnt[l];
    m = (m < CAP) ? m : CAP;
    float4 ss = s_src4[n];

    // ---- Phase A: weights into wave-private LDS, rowsums in registers ----
    float p0 = 0.f, p1 = 0.f, p2 = 0.f, p3 = 0.f;
    for (int j = lane; j < m; j += 64) {
      int d = nbkt[l][j];
      float4 sd = s_dst4[d];
      float sc0 = ss.x + sd.x, sc1 = ss.y + sd.y, sc2 = ss.z + sd.z, sc3 = ss.w + sd.w;
      float e0 = __expf(-fmaxf(sc0, 0.2f * sc0));
      float e1 = __expf(-fmaxf(sc1, 0.2f * sc1));
      float e2 = __expf(-fmaxf(sc2, 0.2f * sc2));
      float e3 = __expf(-fmaxf(sc3, 0.2f * sc3));
      lds_w[ws][j] = make_float4(e0, e1, e2, e3);
      p0 += e0; p1 += e1; p2 += e2; p3 += e3;
    }
#pragma unroll
    for (int off = 32; off > 0; off >>= 1) {
      p0 += __shfl_xor(p0, off, 64);
      p1 += __shfl_xor(p1, off, 64);
      p2 += __shfl_xor(p2, off, 64);
      p3 += __shfl_xor(p3, off, 64);
    }

    // ---- Phase B: x-gather + FMA, unroll x2 ----
    float2 a0 = {0.f, 0.f}, a1 = {0.f, 0.f}, a2 = {0.f, 0.f}, a3 = {0.f, 0.f};
    int j = 0;
    for (; j + 1 < m; j += 2) {
      int d0 = nbkt[l][j];
      int d1 = nbkt[l][j + 1];
      float4 w0 = lds_w[ws][j];
      float4 w1 = lds_w[ws][j + 1];
      float2 x0 = *(const float2*)(xp + (size_t)d0 * F_OUT);
      float2 x1 = *(const float2*)(xp + (size_t)d1 * F_OUT);
      a0.x = fmaf(w0.x, x0.x, a0.x); a0.y = fmaf(w0.x, x0.y, a0.y);
      a1.x = fmaf(w0.y, x0.x, a1.x); a1.y = fmaf(w0.y, x0.y, a1.y);
      a2.x = fmaf(w0.z, x0.x, a2.x); a2.y = fmaf(w0.z, x0.y, a2.y);
      a3.x = fmaf(w0.w, x0.x, a3.x); a3.y = fmaf(w0.w, x0.y, a3.y);
      a0.x = fmaf(w1.x, x1.x, a0.x); a0.y = fmaf(w1.x, x1.y, a0.y);
      a1.x = fmaf(w1.y, x1.x, a1.x); a1.y = fmaf(w1.y, x1.y, a1.y);
      a2.x = fmaf(w1.z, x1.x, a2.x); a2.y = fmaf(w1.z, x1.y, a2.y);
      a3.x = fmaf(w1.w, x1.x, a3.x); a3.y = fmaf(w1.w, x1.y, a3.y);
    }
    if (j < m) {
      int d0 = nbkt[l][j];
      float4 w0 = lds_w[ws][j];
      float2 x0 = *(const float2*)(xp + (size_t)d0 * F_OUT);
      a0.x = fmaf(w0.x, x0.x, a0.x); a0.y = fmaf(w0.x, x0.y, a0.y);
      a1.x = fmaf(w0.y, x0.x, a1.x); a1.y = fmaf(w0.y, x0.y, a1.y);
      a2.x = fmaf(w0.z, x0.x, a2.x); a2.y = fmaf(w0.z, x0.y, a2.y);
      a3.x = fmaf(w0.w, x0.x, a3.x); a3.y = fmaf(w0.w, x0.y, a3.y);
    }

    // ---- epilogue ----
    const float2 wl0 = *(const float2*)(w + 0 * F_OUT + 2 * lane);
    const float2 wl1 = *(const float2*)(w + 1 * F_OUT + 2 * lane);
    const float2 wl2 = *(const float2*)(w + 2 * F_OUT + 2 * lane);
    const float2 wl3 = *(const float2*)(w + 3 * F_OUT + 2 * lane);
    float r0 = 1.f / p0, r1 = 1.f / p1, r2 = 1.f / p2, r3 = 1.f / p3;

    float2 o;
    o.x = wl0.x * a0.x * r0; o.y = wl0.y * a0.y * r0;
    *(float2*)(out + ((size_t)0 * N_NODES + n) * F_OUT + 2 * lane) = o;
    o.x = wl1.x * a1.x * r1; o.y = wl1.y * a1.y * r1;
    *(float2*)(out + ((size_t)1 * N_NODES + n) * F_OUT + 2 * lane) = o;
    o.x = wl2.x * a2.x * r2; o.y = wl2.y * a2.y * r2;
    *(float2*)(out + ((size_t)2 * N_NODES + n) * F_OUT + 2 * lane) = o;
    o.x = wl3.x * a3.x * r3; o.y = wl3.y * a3.y * r3;
    *(float2*)(out + ((size_t)3 * N_NODES + n) * F_OUT + 2 * lane) = o;
  }
}

extern "C" void kernel_launch(void* const* d_in, const int* in_sizes, int n_in,
                              void* d_out, int out_size, void* d_ws, size_t ws_size,
                              hipStream_t stream) {
  const float* x = (const float*)d_in[0];
  const float* w = (const float*)d_in[1];
  const float* a = (const float*)d_in[2];
  const int* ei = (const int*)d_in[3];
  const int* src = ei;
  const int* dst = ei + N_EDGES;
  float* out = (float*)d_out;

  char* p = (char*)d_ws;
  float4* s_src4 = (float4*)p;      p += (size_t)N_NODES * 16;
  float4* s_dst4 = (float4*)p;      p += (size_t)N_NODES * 16;
  int* gc = (int*)p;                p += 4096;                        // K1 counters
  unsigned int* region = (unsigned int*)p;
  p += (size_t)K1 * SCAP * 4;                                        // 6.8 MB

  hipMemsetAsync(gc, 0, 4096, stream);

  score_kernel<<<(N_NODES * 64 + 255) / 256, 256, 0, stream>>>(x, w, a, s_src4, s_dst4);
  partition_kernel<<<P1_BLOCKS, 256, 0, stream>>>(src, dst, gc, region);
  agg_kernel<<<GROUPS, 256, 0, stream>>>(x, w, s_src4, s_dst4, gc, region, out);
}